// Round 1
// baseline (1448.093 us; speedup 1.0000x reference)
//
#include <hip/hip_runtime.h>

#define BATCH 16
#define SEQ 8192
#define CH 32
#define NB 24

__device__ __forceinline__ float rcp_fast(float x) { return __builtin_amdgcn_rcpf(x); }

__device__ __forceinline__ float fast_tanh(float x) {
    // tanh(x) = sign(x) * (1 - e^{-2|x|}) / (1 + e^{-2|x|}); e <= 1, no overflow
    float ax = fabsf(x);
    float e = __expf(-2.0f * ax);
    float t = (1.0f - e) * rcp_fast(1.0f + e);
    return copysignf(t, x);
}

__device__ __forceinline__ float fast_sigmoid(float x) {
    return rcp_fast(1.0f + __expf(-x));
}

// ---------------- initial causal conv (1 -> 32 ch, K=2, dil=1) + zero skip_sum
__global__ __launch_bounds__(256) void k_init(const float* __restrict__ x,
                                              const float* __restrict__ W0,
                                              const float* __restrict__ b0,
                                              float* __restrict__ h,
                                              float* __restrict__ ss) {
    int idx = blockIdx.x * 256 + threadIdx.x;          // 0 .. BATCH*SEQ-1
    int b = idx >> 13, t = idx & (SEQ - 1);
    float xt = x[b * SEQ + t];
    float xm = (t > 0) ? x[b * SEQ + t - 1] : 0.0f;
#pragma unroll
    for (int c = 0; c < CH; ++c) {
        float v = W0[c * 2 + 0] * xm + W0[c * 2 + 1] * xt + b0[c];
        h[(b * CH + c) * SEQ + t] = v;
        ss[(b * CH + c) * SEQ + t] = 0.0f;
    }
}

// ---------------- one WaveNet block: dilated conv(32->64) -> gate -> 1x1 skip
// -> residual h update + skip_sum accumulate.  hin/hout ping-pong (RAW safety).
__global__ __launch_bounds__(256) void k_block(const float* __restrict__ hin,
                                               float* __restrict__ hout,
                                               float* __restrict__ ss,
                                               const float* __restrict__ Wd,   // (64,32,2)
                                               const float* __restrict__ bd,   // (64)
                                               const float* __restrict__ W1,   // (32,32)
                                               const float* __restrict__ b1,   // (32)
                                               int dil) {
    int idx = blockIdx.x * 256 + threadIdx.x;
    int b = idx >> 13, t = idx & (SEQ - 1);
    const float* hb = hin + b * CH * SEQ + t;

    float ht[CH], htd[CH];
    bool ok = (t >= dil);
#pragma unroll
    for (int c = 0; c < CH; ++c) {
        ht[c] = hb[c * SEQ];
        htd[c] = ok ? hb[c * SEQ - dil] : 0.0f;
    }

    float skip[CH];
#pragma unroll
    for (int o = 0; o < CH; ++o) skip[o] = b1[o];

#pragma unroll 1
    for (int c = 0; c < CH; ++c) {                  // output channel of gate (rolled)
        float f = bd[c], g = bd[c + CH];
        const float* wf_ = Wd + c * (CH * 2);       // row c      : filter
        const float* wg_ = Wd + (c + CH) * (CH * 2);// row c + 32 : gate
        // split into two partial sums per chain for ILP
        float f1 = 0.0f, g1 = 0.0f;
#pragma unroll
        for (int cc = 0; cc < CH; cc += 2) {
            f  += wf_[cc * 2 + 0] * htd[cc]     + wf_[cc * 2 + 1] * ht[cc];
            f1 += wf_[cc * 2 + 2] * htd[cc + 1] + wf_[cc * 2 + 3] * ht[cc + 1];
            g  += wg_[cc * 2 + 0] * htd[cc]     + wg_[cc * 2 + 1] * ht[cc];
            g1 += wg_[cc * 2 + 2] * htd[cc + 1] + wg_[cc * 2 + 3] * ht[cc + 1];
        }
        f += f1; g += g1;
        float gated = fast_tanh(f) * fast_sigmoid(g);
#pragma unroll
        for (int o = 0; o < CH; ++o) skip[o] += W1[o * CH + c] * gated;
    }

    float* ho = hout + b * CH * SEQ + t;
    float* sp = ss + b * CH * SEQ + t;
#pragma unroll
    for (int o = 0; o < CH; ++o) {
        ho[o * SEQ] = ht[o] + skip[o];
        sp[o * SEQ] += skip[o];
    }
}

// ---------------- relu(skip_sum) -> Wf GEMM -> relu -> maxpool(L/4 chunks)
__global__ __launch_bounds__(256) void k_final1(const float* __restrict__ ss,
                                                const float* __restrict__ Wf,  // (32,32)
                                                const float* __restrict__ bf,
                                                float* __restrict__ pooled) {  // (B,32,4)
    int b = blockIdx.x >> 2, q = blockIdx.x & 3;
    int tid = threadIdx.x;
    const float* sb = ss + b * CH * SEQ + q * (SEQ / 4);

    float ymax[CH];
#pragma unroll
    for (int o = 0; o < CH; ++o) ymax[o] = -1e30f;

#pragma unroll 1
    for (int k = 0; k < (SEQ / 4) / 256; ++k) {     // 8 positions per thread
        int t = k * 256 + tid;
        float r[CH];
#pragma unroll
        for (int c = 0; c < CH; ++c) r[c] = fmaxf(sb[c * SEQ + t], 0.0f);
#pragma unroll
        for (int o = 0; o < CH; ++o) {
            float acc = bf[o];
#pragma unroll
            for (int c = 0; c < CH; ++c) acc += Wf[o * CH + c] * r[c];
            ymax[o] = fmaxf(ymax[o], fmaxf(acc, 0.0f));
        }
    }

    // wave butterfly max-reduce (64 lanes)
#pragma unroll
    for (int o = 0; o < CH; ++o) {
#pragma unroll
        for (int off = 32; off >= 1; off >>= 1)
            ymax[o] = fmaxf(ymax[o], __shfl_xor(ymax[o], off));
    }

    __shared__ float red[4 * CH];
    int wave = tid >> 6, lane = tid & 63;
    if (lane == 0) {
#pragma unroll
        for (int o = 0; o < CH; ++o) red[wave * CH + o] = ymax[o];
    }
    __syncthreads();
    if (tid < CH) {
        float m = fmaxf(fmaxf(red[tid], red[CH + tid]),
                        fmaxf(red[2 * CH + tid], red[3 * CH + tid]));
        pooled[b * (CH * 4) + tid * 4 + q] = m;   // layout (B, c*4+q) matches reshape
    }
}

// ---------------- final MLP: (B,128) -> relu FC 64 -> FC 10
__global__ __launch_bounds__(1024) void k_final2(const float* __restrict__ pooled,
                                                 const float* __restrict__ fW1, // (64,128)
                                                 const float* __restrict__ fb1,
                                                 const float* __restrict__ fW2, // (10,64)
                                                 const float* __restrict__ fb2,
                                                 float* __restrict__ out) {
    __shared__ float y1[BATCH * 64];
    int tid = threadIdx.x;
    int b = tid >> 6, o = tid & 63;
    float acc = fb1[o];
#pragma unroll
    for (int j = 0; j < 128; ++j) acc += fW1[o * 128 + j] * pooled[b * 128 + j];
    y1[b * 64 + o] = fmaxf(acc, 0.0f);
    __syncthreads();
    if (tid < BATCH * 10) {
        int bb = tid / 10, o2 = tid % 10;
        float a2 = fb2[o2];
#pragma unroll
        for (int j = 0; j < 64; ++j) a2 += fW2[o2 * 64 + j] * y1[bb * 64 + j];
        out[bb * 10 + o2] = a2;
    }
}

extern "C" void kernel_launch(void* const* d_in, const int* in_sizes, int n_in,
                              void* d_out, int out_size, void* d_ws, size_t ws_size,
                              hipStream_t stream) {
    const float* x   = (const float*)d_in[0];
    const float* W0  = (const float*)d_in[1];
    const float* b0  = (const float*)d_in[2];
    const float* Wd  = (const float*)d_in[3];
    const float* bd  = (const float*)d_in[4];
    const float* W1  = (const float*)d_in[5];
    const float* b1  = (const float*)d_in[6];
    const float* Wf  = (const float*)d_in[7];
    const float* bf  = (const float*)d_in[8];
    const float* fW1 = (const float*)d_in[9];
    const float* fb1 = (const float*)d_in[10];
    const float* fW2 = (const float*)d_in[11];
    const float* fb2 = (const float*)d_in[12];
    float* out = (float*)d_out;

    const size_t HS = (size_t)BATCH * CH * SEQ;    // 4 M floats = 16 MB
    float* h0 = (float*)d_ws;
    float* h1 = h0 + HS;
    float* ss = h1 + HS;
    float* pooled = ss + HS;

    const int grid = BATCH * SEQ / 256;            // 512

    k_init<<<grid, 256, 0, stream>>>(x, W0, b0, h0, ss);

    const float* hin = h0;
    float* hout = h1;
    for (int i = 0; i < NB; ++i) {
        int dil = 1 << (i & 7);
        k_block<<<grid, 256, 0, stream>>>(hin, hout, ss,
                                          Wd + (size_t)i * 64 * CH * 2,
                                          bd + (size_t)i * 64,
                                          W1 + (size_t)i * CH * CH,
                                          b1 + (size_t)i * CH, dil);
        const float* tmp = hout; hout = (float*)hin; hin = tmp;
    }

    k_final1<<<BATCH * 4, 256, 0, stream>>>(ss, Wf, bf, pooled);
    k_final2<<<1, 1024, 0, stream>>>(pooled, fW1, fb1, fW2, fb2, out);
}